// Round 18
// baseline (222.077 us; speedup 1.0000x reference)
//
#include <hip/hip_runtime.h>
#include <hip/hip_cooperative_groups.h>
#include <stdint.h>

namespace cg = cooperative_groups;

// out = dequant( int8(lhs*ls) @ int8(rhs*rs) ) / (ls*rs), 4096^3, fp32 in/out.
// ls = 127 / max(amax|lhs|, 1e-12). Int core is bit-exact vs numpy (RNE quant).
//
// Workspace: [0,16Mi) qA frag-order ; [16Mi,32Mi) qBT frag-order ; 2x u32 amax.
//
// v17 = v16 GEMM (best: 71.3us; 128x256 tile, 4 waves, frag-ordered
// workspace, 32x32x32 MFMA, A linear-LDS prefetch-1, B global-direct register
// prefetch, BK=256 windows, 2 blocks/CU) + FUSED PREPROCESSING: absmax and
// quant merged into one cooperative kernel (grid.sync() between phases).
// Rationale: GEMM improved 91->71us across 16 rounds while totals moved only
// ~10us -- the non-GEMM floor (~59-69us: absmax ~21us HBM-bound + quant
// ~15-20us + memset + THREE dispatch boundaries/ramps) now rivals the GEMM.
// Fusion removes one boundary + launch ramp and guarantees quant reads
// L3-warm data. All arithmetic is bit-identical to the verified kernels;
// only launch topology changes. Co-residency: 1024 blocks x 256 thr at
// 4.4 KB LDS -> <=8 blocks/CU capacity, 1024 << 2048.
//
// Layouts (all harness-verified, absmax 0.0 in v8/v10-v16):
//   frag (t_g, ks_g) at ((t_g*128 + ks_g)*64 + lane)*16; lane l holds
//   [t_g*32+(l&31)][ks_g*32+(l>>5)*16 .. +16).
//   C/D 32x32: col = lane&31, row = (reg&3) + 8*(reg>>2) + 4*(lane>>5).

#define NROW 4096
#define NELEM (4096 * 4096)

typedef __attribute__((ext_vector_type(4))) int int32x4;
typedef __attribute__((ext_vector_type(16))) int int32x16;
typedef const __attribute__((address_space(1))) int8_t* gptr1_t;
typedef __attribute__((address_space(3))) int8_t* lptr3_t;

__device__ __forceinline__ int q8(float v, float s) {
    int r = __float2int_rn(v * s);  // RNE, matches jnp.round
    r = r < -127 ? -127 : r;
    r = r > 127 ? 127 : r;
    return r;
}

__device__ __forceinline__ int pack4(float a, float b, float c, float d,
                                     float s) {
    return (q8(a, s) & 0xff) | ((q8(b, s) & 0xff) << 8) |
           ((q8(c, s) & 0xff) << 16) | ((q8(d, s) & 0xff) << 24);
}

// ONE cooperative kernel, 1024 blocks x 256 threads.
// Phase 1 (absmax, math identical to the verified absmax_both_kernel):
//   even blocks -> lhs, odd -> rhs; 512 blocks/tensor; 4-way unrolled
//   strided float4 max-reduce; wave shuffle + LDS + atomicMax on fp32 bits.
// grid.sync()
// Phase 2 (quant, math identical to the verified quant_kernel):
//   blocks [0,512): A -> frag layout, 8 x 256-chunk groups each.
//   blocks [512,1024): B -> LDS 64x64 transpose, 8 tiles each, frag-order
//   output; extra __syncthreads() between tiles for LDS WAR.
__global__ void fused_pre_kernel(const float* __restrict__ lhs,
                                 const float* __restrict__ rhs,
                                 int8_t* __restrict__ qA,
                                 int8_t* __restrict__ qT,
                                 unsigned* __restrict__ amax) {
    __shared__ int8_t sm[64][68];
    __shared__ float red[4];

    // ---- Phase 1: absmax ----
    {
        const int t = blockIdx.x & 1;
        const float4* x4 = (const float4*)(t ? rhs : lhs);
        const int bid = blockIdx.x >> 1;
        const int stride = (gridDim.x >> 1) * blockDim.x;  // 131072
        int i = bid * blockDim.x + threadIdx.x;
        float m0 = 0.0f, m1 = 0.0f, m2 = 0.0f, m3 = 0.0f;
        for (; i + 3 * stride < NELEM / 4; i += 4 * stride) {
            float4 a = x4[i];
            float4 b = x4[i + stride];
            float4 c = x4[i + 2 * stride];
            float4 d = x4[i + 3 * stride];
            m0 = fmaxf(m0, fmaxf(fmaxf(fabsf(a.x), fabsf(a.y)),
                                 fmaxf(fabsf(a.z), fabsf(a.w))));
            m1 = fmaxf(m1, fmaxf(fmaxf(fabsf(b.x), fabsf(b.y)),
                                 fmaxf(fabsf(b.z), fabsf(b.w))));
            m2 = fmaxf(m2, fmaxf(fmaxf(fabsf(c.x), fabsf(c.y)),
                                 fmaxf(fabsf(c.z), fabsf(c.w))));
            m3 = fmaxf(m3, fmaxf(fmaxf(fabsf(d.x), fabsf(d.y)),
                                 fmaxf(fabsf(d.z), fabsf(d.w))));
        }
        for (; i < NELEM / 4; i += stride) {
            float4 a = x4[i];
            m0 = fmaxf(m0, fmaxf(fmaxf(fabsf(a.x), fabsf(a.y)),
                                 fmaxf(fabsf(a.z), fabsf(a.w))));
        }
        float m = fmaxf(fmaxf(m0, m1), fmaxf(m2, m3));
        for (int off = 32; off > 0; off >>= 1)
            m = fmaxf(m, __shfl_down(m, off, 64));
        const int lane = threadIdx.x & 63, wave = threadIdx.x >> 6;
        if (lane == 0) red[wave] = m;
        __syncthreads();
        if (threadIdx.x == 0) {
            float b = fmaxf(fmaxf(red[0], red[1]), fmaxf(red[2], red[3]));
            atomicMax(amax + t, __float_as_uint(b));  // bits monotone for >=0
        }
    }

    cg::this_grid().sync();

    // ---- Phase 2: quant ----
    if (blockIdx.x < 512) {
        const float s = 127.0f / fmaxf(__uint_as_float(amax[0]), 1e-12f);
#pragma unroll 1
        for (int it = 0; it < 8; ++it) {
            const int c = (blockIdx.x * 8 + it) * 256 + threadIdx.x;
            const int l = c & 63;
            const int ks_g = (c >> 6) & 127;
            const int mt_g = c >> 13;
            const int row = mt_g * 32 + (l & 31);
            const int kb = ks_g * 32 + (l >> 5) * 16;
            const float4* src = (const float4*)(lhs + (size_t)row * NROW + kb);
            float4 v0 = src[0], v1 = src[1], v2 = src[2], v3 = src[3];
            int4 w;
            w.x = pack4(v0.x, v0.y, v0.z, v0.w, s);
            w.y = pack4(v1.x, v1.y, v1.z, v1.w, s);
            w.z = pack4(v2.x, v2.y, v2.z, v2.w, s);
            w.w = pack4(v3.x, v3.y, v3.z, v3.w, s);
            *(int4*)(qA + (size_t)c * 16) = w;
        }
    } else {
        const float s = 127.0f / fmaxf(__uint_as_float(amax[1]), 1e-12f);
#pragma unroll 1
        for (int it = 0; it < 8; ++it) {
            const int b = (blockIdx.x - 512) * 8 + it;
            const int n0 = (b & 63) * 64, k0 = (b >> 6) * 64;
            const int rl = threadIdx.x >> 4;   // k row within 16-row slab
            const int nq = threadIdx.x & 15;   // float4 column
            for (int r = 0; r < 4; ++r) {
                const int kl = r * 16 + rl;
                float4 v = *(const float4*)(rhs + (size_t)(k0 + kl) * NROW +
                                            n0 + nq * 4);
                sm[nq * 4 + 0][kl] = (int8_t)q8(v.x, s);
                sm[nq * 4 + 1][kl] = (int8_t)q8(v.y, s);
                sm[nq * 4 + 2][kl] = (int8_t)q8(v.z, s);
                sm[nq * 4 + 3][kl] = (int8_t)q8(v.w, s);
            }
            __syncthreads();
            // Frag-order store: tile = 2 nt x 2 ks x 64 lanes = 256 chunks.
            const int nt_l = threadIdx.x >> 7;        // 0..1
            const int ks_l = (threadIdx.x >> 6) & 1;  // 0..1
            const int l = threadIdx.x & 63;
            const int n_loc = nt_l * 32 + (l & 31);
            const int k_loc = ks_l * 32 + (l >> 5) * 16;
            int4 w;  // 4x b32 reads, stride 17 words -> conflict-free
            w.x = *(const int*)&sm[n_loc][k_loc + 0];
            w.y = *(const int*)&sm[n_loc][k_loc + 4];
            w.z = *(const int*)&sm[n_loc][k_loc + 8];
            w.w = *(const int*)&sm[n_loc][k_loc + 12];
            const int nt_g = (b & 63) * 2 + nt_l;
            const int ks_g = (b >> 6) * 2 + ks_l;
            *(int4*)(qT + (((size_t)nt_g * 128 + ks_g) * 64 + l) * 16) = w;
            __syncthreads();  // LDS WAR before next tile's writes
        }
    }
}

// 128x256 tile, 4 waves (1Mx4N of 128x64 = 4x2 of 32x32), BK=256 windows
// (2 K-tiles of 128 per barrier), 2 blocks/CU. A: double-buffered frag-
// ordered LDS (2 x 32 KiB), prefetch-1 window. B: global-direct register
// frags, 2-ks prefetch across 4 quarter-phases. Window w (tiles 2w, 2w+1):
// [stage A(w+1) both sub-tiles; {LOADB next; HALF} x4; vmcnt(4); s_barrier].
// (v16-verified, byte-identical.)
__global__ __launch_bounds__(256, 2) void gemm_i8_kernel(
    const int8_t* __restrict__ qA, const int8_t* __restrict__ qBT,
    float* __restrict__ out, const unsigned* __restrict__ amax) {
    __shared__ __align__(16) int8_t sA[2][32768];

    const int tid = threadIdx.x;
    const int lane = tid & 63;
    const int wn = tid >> 6;        // 0..3 : 64-col sub-tile

    // XCD-aware bijective swizzle (grid 512, 512%8==0): XCD k gets swz ids
    // [64k,64k+64) -> 4 contiguous 128-row M-panels (2 MB A) L2-resident.
    const int bid = blockIdx.y * 16 + blockIdx.x;
    const int swz = (bid & 7) * 64 + (bid >> 3);
    const int m0 = (swz >> 4) * 128, n0 = (swz & 15) * 256;

    const int rl = lane & 31;       // row within a 32-row MFMA tile
    const int hi = lane >> 5;       // k-half selector

    const gptr1_t pA0 = (gptr1_t)(qA + (size_t)(m0 / 32) * 131072 + tid * 16);
    int8_t* sAf = &sA[0][0];
    const int dst0 = tid * 16;

    auto stage = [&](int slot, int w1) {
#pragma unroll
        for (int h = 0; h < 2; ++h) {
            const int kb = (2 * w1 + h) * 4096;
#pragma unroll
            for (int j = 0; j < 4; ++j) {
                __builtin_amdgcn_global_load_lds(
                    pA0 + (size_t)j * 131072 + kb,
                    (lptr3_t)(sAf + slot * 32768 + h * 16384 + dst0 + j * 4096),
                    16, 0, 0);
            }
        }
    };

    const int8_t* pbW = qBT + (size_t)(n0 / 32 + wn * 2) * 131072 + lane * 16;

    int32x16 acc[4][2];
#pragma unroll
    for (int mt = 0; mt < 4; ++mt)
#pragma unroll
        for (int nt = 0; nt < 2; ++nt) acc[mt][nt] = (int32x16)(0);

    const int aBase = lane * 16;

    int32x4 B0[4], B1[4];  // [nt*2 + k] for a 2-ks quarter-phase

#define LOADB(B, KT, KS0)                                                     \
    {                                                                         \
        const int8_t* bp = pbW + (size_t)(KT)*4096 + (KS0)*1024;              \
        B[0] = *(const int32x4*)(bp);                                         \
        B[1] = *(const int32x4*)(bp + 1024);                                  \
        B[2] = *(const int32x4*)(bp + 131072);                                \
        B[3] = *(const int32x4*)(bp + 131072 + 1024);                         \
    }

#define HALF(APTR, B, KS0)                                                    \
    {                                                                         \
        _Pragma("unroll") for (int k = 0; k < 2; ++k) {                       \
            int32x4 af[4];                                                    \
            _Pragma("unroll") for (int mt = 0; mt < 4; ++mt) af[mt] =         \
                *(const int32x4*)((APTR) + aBase + mt * 4096 +                \
                                  ((KS0) + k) * 1024);                        \
            __builtin_amdgcn_s_setprio(1);                                    \
            _Pragma("unroll") for (int mt = 0; mt < 4; ++mt)                  \
                _Pragma("unroll") for (int nt = 0; nt < 2; ++nt)              \
                    acc[mt][nt] = __builtin_amdgcn_mfma_i32_32x32x32_i8(      \
                        af[mt], B[nt * 2 + k], acc[mt][nt], 0, 0, 0);         \
            __builtin_amdgcn_s_setprio(0);                                    \
        }                                                                     \
    }

    // Prologue: stage A window 0 (tiles 0,1); load B ks=0,1 of tile 0;
    // drain; barrier.
    stage(0, 0);
    __builtin_amdgcn_sched_barrier(0);
    LOADB(B0, 0, 0)
    asm volatile("s_waitcnt vmcnt(0)" ::: "memory");
    __builtin_amdgcn_sched_barrier(0);
    __builtin_amdgcn_s_barrier();
    __builtin_amdgcn_sched_barrier(0);

    // 16 windows of BK=256. Windows 0..14 stage the next window; 15 below.
#pragma unroll 1
    for (int w = 0; w < 15; ++w) {
        const int8_t* a0 = sAf + (w & 1) * 32768;
        const int8_t* a1 = a0 + 16384;
        stage((w + 1) & 1, w + 1);
        __builtin_amdgcn_sched_barrier(0);
        LOADB(B1, 2 * w, 2)           // tile 2w, ks 2,3
        HALF(a0, B0, 0)               // tile 2w, ks 0,1
        LOADB(B0, 2 * w + 1, 0)       // tile 2w+1, ks 0,1
        HALF(a0, B1, 2)               // tile 2w, ks 2,3
        LOADB(B1, 2 * w + 1, 2)       // tile 2w+1, ks 2,3
        HALF(a1, B0, 0)               // tile 2w+1, ks 0,1
        LOADB(B0, 2 * w + 2, 0)       // next window, tile 2w+2, ks 0,1
        HALF(a1, B1, 2)               // tile 2w+1, ks 2,3 (wait drains stage)
        asm volatile("s_waitcnt vmcnt(4)" ::: "memory");  // keep only B0(next)
        __builtin_amdgcn_sched_barrier(0);
        __builtin_amdgcn_s_barrier();
        __builtin_amdgcn_sched_barrier(0);
    }
    // Window 15 (slot 1, tiles 30,31): no staging, no next-window B.
    {
        const int8_t* a0 = sAf + 32768;
        const int8_t* a1 = a0 + 16384;
        LOADB(B1, 30, 2)
        HALF(a0, B0, 0)
        LOADB(B0, 31, 0)
        HALF(a0, B1, 2)
        LOADB(B1, 31, 2)
        HALF(a1, B0, 0)
        HALF(a1, B1, 2)
    }

    // Epilogue: dequant + store. 32x32 C/D layout: col = lane&31,
    // row = (reg&3) + 8*(reg>>2) + 4*(lane>>5). (v8/v12-v16-verified.)
    const float ls = 127.0f / fmaxf(__uint_as_float(amax[0]), 1e-12f);
    const float rs = 127.0f / fmaxf(__uint_as_float(amax[1]), 1e-12f);
    const float inv = 1.0f / (ls * rs);
#pragma unroll
    for (int mt = 0; mt < 4; ++mt)
#pragma unroll
        for (int nt = 0; nt < 2; ++nt)
#pragma unroll
            for (int reg = 0; reg < 16; ++reg) {
                const int row = m0 + mt * 32 + (reg & 3) + 8 * (reg >> 2) +
                                4 * hi;
                const int col = n0 + wn * 64 + nt * 32 + rl;
                out[(size_t)row * NROW + col] = (float)acc[mt][nt][reg] * inv;
            }
#undef LOADB
#undef HALF
}

extern "C" void kernel_launch(void* const* d_in, const int* in_sizes, int n_in,
                              void* d_out, int out_size, void* d_ws,
                              size_t ws_size, hipStream_t stream) {
    const float* lhs = (const float*)d_in[0];
    const float* rhs = (const float*)d_in[1];
    float* out = (float*)d_out;

    int8_t* qA = (int8_t*)d_ws;
    int8_t* qBT = qA + (size_t)16 * 1024 * 1024;
    unsigned* amax = (unsigned*)(qBT + (size_t)16 * 1024 * 1024);

    hipMemsetAsync(amax, 0, 8, stream);

    void* kargs[] = {(void*)&lhs, (void*)&rhs, (void*)&qA, (void*)&qBT,
                     (void*)&amax};
    hipLaunchCooperativeKernel((void*)fused_pre_kernel, dim3(1024), dim3(256),
                               kargs, 0, stream);

    gemm_i8_kernel<<<dim3(16, 32), 256, 0, stream>>>(qA, qBT, out, amax);
}

// Round 19
// 137.535 us; speedup vs baseline: 1.6147x; 1.6147x over previous
//
#include <hip/hip_runtime.h>
#include <stdint.h>

// out = dequant( int8(lhs*ls) @ int8(rhs*rs) ) / (ls*rs), 4096^3, fp32 in/out.
// ls = 127 / max(amax|lhs|, 1e-12). Int core is bit-exact vs numpy (RNE quant).
//
// Workspace: [0,16Mi) qA frag-order ; [16Mi,32Mi) qBT frag-order ; 2x u32 amax.
//
// v19 = REVERT to v16 (best measured configuration: 137.9us total, GEMM
// 71.3us). Round 18's cooperative absmax+quant fusion regressed badly:
// grid.sync() cost ~115us on-device (1024 blocks spinning device-scope
// atomics across 8 non-coherent XCD L2s; VALUBusy 4.6%) vs the ~5us
// dispatch boundary it saved. The phase boundary is better left as a kernel
// boundary.
//
// GEMM (v16): 128x256 tile, 4 waves (1Mx4N of 128x64), frag-ordered
// workspace, mfma_i32_32x32x32_i8, A via conflict-free linear LDS
// (prefetch-1 window, double-buffered 2x32KiB), B global-direct register
// prefetch (2-ks ahead), BK=256 windows (one barrier per 2 K-tiles),
// 2 blocks/CU for cross-domain MFMA/mem overlap, XCD-aware swizzle.
// Measured optima along every explored axis: barrier domains/CU = 2
// (v13:1=78.5, v14:2=72.5, v15:4=83.4); BK = 256 (v14:128=72.5,
// v16:256=71.3); MFMA = 32x32x32 with frag-ordered LDS (v12).
//
// Layouts (all harness-verified, absmax 0.0 in v8/v10-v17):
//   frag (t_g, ks_g) at ((t_g*128 + ks_g)*64 + lane)*16; lane l holds
//   [t_g*32+(l&31)][ks_g*32+(l>>5)*16 .. +16).
//   C/D 32x32: col = lane&31, row = (reg&3) + 8*(reg>>2) + 4*(lane>>5).

#define NROW 4096
#define NELEM (4096 * 4096)

typedef __attribute__((ext_vector_type(4))) int int32x4;
typedef __attribute__((ext_vector_type(16))) int int32x16;
typedef const __attribute__((address_space(1))) int8_t* gptr1_t;
typedef __attribute__((address_space(3))) int8_t* lptr3_t;

__global__ void absmax_both_kernel(const float* __restrict__ lhs,
                                   const float* __restrict__ rhs,
                                   unsigned* __restrict__ amax) {
    __shared__ float red[4];
    const int t = blockIdx.x & 1;
    const float4* x4 = (const float4*)(t ? rhs : lhs);
    const int bid = blockIdx.x >> 1;
    const int stride = (gridDim.x >> 1) * blockDim.x;  // 262144
    int i = bid * blockDim.x + threadIdx.x;
    float m0 = 0.0f, m1 = 0.0f, m2 = 0.0f, m3 = 0.0f;
    for (; i + 3 * stride < NELEM / 4; i += 4 * stride) {
        float4 a = x4[i];
        float4 b = x4[i + stride];
        float4 c = x4[i + 2 * stride];
        float4 d = x4[i + 3 * stride];
        m0 = fmaxf(m0, fmaxf(fmaxf(fabsf(a.x), fabsf(a.y)),
                             fmaxf(fabsf(a.z), fabsf(a.w))));
        m1 = fmaxf(m1, fmaxf(fmaxf(fabsf(b.x), fabsf(b.y)),
                             fmaxf(fabsf(b.z), fabsf(b.w))));
        m2 = fmaxf(m2, fmaxf(fmaxf(fabsf(c.x), fabsf(c.y)),
                             fmaxf(fabsf(c.z), fabsf(c.w))));
        m3 = fmaxf(m3, fmaxf(fmaxf(fabsf(d.x), fabsf(d.y)),
                             fmaxf(fabsf(d.z), fabsf(d.w))));
    }
    for (; i < NELEM / 4; i += stride) {
        float4 a = x4[i];
        m0 = fmaxf(m0, fmaxf(fmaxf(fabsf(a.x), fabsf(a.y)),
                             fmaxf(fabsf(a.z), fabsf(a.w))));
    }
    float m = fmaxf(fmaxf(m0, m1), fmaxf(m2, m3));
    for (int off = 32; off > 0; off >>= 1)
        m = fmaxf(m, __shfl_down(m, off, 64));
    const int lane = threadIdx.x & 63, wave = threadIdx.x >> 6;
    if (lane == 0) red[wave] = m;
    __syncthreads();
    if (threadIdx.x == 0) {
        float b = fmaxf(fmaxf(red[0], red[1]), fmaxf(red[2], red[3]));
        atomicMax(amax + t, __float_as_uint(b));  // |x|>=0: bits monotone as uint
    }
}

__device__ __forceinline__ int q8(float v, float s) {
    int r = __float2int_rn(v * s);  // RNE, matches jnp.round
    r = r < -127 ? -127 : r;
    r = r > 127 ? 127 : r;
    return r;
}

__device__ __forceinline__ int pack4(float a, float b, float c, float d,
                                     float s) {
    return (q8(a, s) & 0xff) | ((q8(b, s) & 0xff) << 8) |
           ((q8(c, s) & 0xff) << 16) | ((q8(d, s) & 0xff) << 24);
}

// Blocks [0,4096): A -> fragment layout (thread t = chunk c: contiguous 16B
// store to qA+c*16 from a 64B row-segment of lhs). Blocks [4096,8192): B ->
// verified LDS 64x64 transpose, frag-order output. (v10-v17 verified.)
__global__ void quant_kernel(const float* __restrict__ lhs,
                             const float* __restrict__ rhs,
                             int8_t* __restrict__ qA, int8_t* __restrict__ qT,
                             const unsigned* __restrict__ amax) {
    __shared__ int8_t sm[64][68];
    if (blockIdx.x < 4096) {
        const float s = 127.0f / fmaxf(__uint_as_float(amax[0]), 1e-12f);
        const int c = blockIdx.x * 256 + threadIdx.x;
        const int l = c & 63;
        const int ks_g = (c >> 6) & 127;
        const int mt_g = c >> 13;
        const int row = mt_g * 32 + (l & 31);
        const int kb = ks_g * 32 + (l >> 5) * 16;
        const float4* src = (const float4*)(lhs + (size_t)row * NROW + kb);
        float4 v0 = src[0], v1 = src[1], v2 = src[2], v3 = src[3];
        int4 w;
        w.x = pack4(v0.x, v0.y, v0.z, v0.w, s);
        w.y = pack4(v1.x, v1.y, v1.z, v1.w, s);
        w.z = pack4(v2.x, v2.y, v2.z, v2.w, s);
        w.w = pack4(v3.x, v3.y, v3.z, v3.w, s);
        *(int4*)(qA + (size_t)c * 16) = w;
    } else {
        const float s = 127.0f / fmaxf(__uint_as_float(amax[1]), 1e-12f);
        const int b = blockIdx.x - 4096;
        const int n0 = (b & 63) * 64, k0 = (b >> 6) * 64;
        const int rl = threadIdx.x >> 4;   // k row within 16-row slab
        const int nq = threadIdx.x & 15;   // float4 column
        for (int r = 0; r < 4; ++r) {
            const int kl = r * 16 + rl;
            float4 v = *(const float4*)(rhs + (size_t)(k0 + kl) * NROW + n0 + nq * 4);
            sm[nq * 4 + 0][kl] = (int8_t)q8(v.x, s);
            sm[nq * 4 + 1][kl] = (int8_t)q8(v.y, s);
            sm[nq * 4 + 2][kl] = (int8_t)q8(v.z, s);
            sm[nq * 4 + 3][kl] = (int8_t)q8(v.w, s);
        }
        __syncthreads();
        // Frag-order store: tile = 2 nt x 2 ks x 64 lanes = 256 chunks.
        const int nt_l = threadIdx.x >> 7;        // 0..1
        const int ks_l = (threadIdx.x >> 6) & 1;  // 0..1
        const int l = threadIdx.x & 63;
        const int n_loc = nt_l * 32 + (l & 31);
        const int k_loc = ks_l * 32 + (l >> 5) * 16;
        int4 w;  // 4x b32 reads, stride 17 words -> conflict-free
        w.x = *(const int*)&sm[n_loc][k_loc + 0];
        w.y = *(const int*)&sm[n_loc][k_loc + 4];
        w.z = *(const int*)&sm[n_loc][k_loc + 8];
        w.w = *(const int*)&sm[n_loc][k_loc + 12];
        const int nt_g = (b & 63) * 2 + nt_l;
        const int ks_g = (b >> 6) * 2 + ks_l;
        *(int4*)(qT + (((size_t)nt_g * 128 + ks_g) * 64 + l) * 16) = w;
    }
}

// 128x256 tile, 4 waves (1Mx4N of 128x64 = 4x2 of 32x32), BK=256 windows
// (2 K-tiles of 128 per barrier), 2 blocks/CU. A: double-buffered frag-
// ordered LDS (2 x 32 KiB), prefetch-1 window. B: global-direct register
// frags, 2-ks prefetch across 4 quarter-phases. Window w (tiles 2w, 2w+1):
// [stage A(w+1) both sub-tiles; {LOADB next; HALF} x4; vmcnt(4); s_barrier].
// (v16-verified, byte-identical.)
__global__ __launch_bounds__(256, 2) void gemm_i8_kernel(
    const int8_t* __restrict__ qA, const int8_t* __restrict__ qBT,
    float* __restrict__ out, const unsigned* __restrict__ amax) {
    __shared__ __align__(16) int8_t sA[2][32768];

    const int tid = threadIdx.x;
    const int lane = tid & 63;
    const int wn = tid >> 6;        // 0..3 : 64-col sub-tile

    // XCD-aware bijective swizzle (grid 512, 512%8==0): XCD k gets swz ids
    // [64k,64k+64) -> 4 contiguous 128-row M-panels (2 MB A) L2-resident.
    const int bid = blockIdx.y * 16 + blockIdx.x;
    const int swz = (bid & 7) * 64 + (bid >> 3);
    const int m0 = (swz >> 4) * 128, n0 = (swz & 15) * 256;

    const int rl = lane & 31;       // row within a 32-row MFMA tile
    const int hi = lane >> 5;       // k-half selector

    const gptr1_t pA0 = (gptr1_t)(qA + (size_t)(m0 / 32) * 131072 + tid * 16);
    int8_t* sAf = &sA[0][0];
    const int dst0 = tid * 16;

    auto stage = [&](int slot, int w1) {
#pragma unroll
        for (int h = 0; h < 2; ++h) {
            const int kb = (2 * w1 + h) * 4096;
#pragma unroll
            for (int j = 0; j < 4; ++j) {
                __builtin_amdgcn_global_load_lds(
                    pA0 + (size_t)j * 131072 + kb,
                    (lptr3_t)(sAf + slot * 32768 + h * 16384 + dst0 + j * 4096),
                    16, 0, 0);
            }
        }
    };

    const int8_t* pbW = qBT + (size_t)(n0 / 32 + wn * 2) * 131072 + lane * 16;

    int32x16 acc[4][2];
#pragma unroll
    for (int mt = 0; mt < 4; ++mt)
#pragma unroll
        for (int nt = 0; nt < 2; ++nt) acc[mt][nt] = (int32x16)(0);

    const int aBase = lane * 16;

    int32x4 B0[4], B1[4];  // [nt*2 + k] for a 2-ks quarter-phase

#define LOADB(B, KT, KS0)                                                     \
    {                                                                         \
        const int8_t* bp = pbW + (size_t)(KT)*4096 + (KS0)*1024;              \
        B[0] = *(const int32x4*)(bp);                                         \
        B[1] = *(const int32x4*)(bp + 1024);                                  \
        B[2] = *(const int32x4*)(bp + 131072);                                \
        B[3] = *(const int32x4*)(bp + 131072 + 1024);                         \
    }

#define HALF(APTR, B, KS0)                                                    \
    {                                                                         \
        _Pragma("unroll") for (int k = 0; k < 2; ++k) {                       \
            int32x4 af[4];                                                    \
            _Pragma("unroll") for (int mt = 0; mt < 4; ++mt) af[mt] =         \
                *(const int32x4*)((APTR) + aBase + mt * 4096 +                \
                                  ((KS0) + k) * 1024);                        \
            __builtin_amdgcn_s_setprio(1);                                    \
            _Pragma("unroll") for (int mt = 0; mt < 4; ++mt)                  \
                _Pragma("unroll") for (int nt = 0; nt < 2; ++nt)              \
                    acc[mt][nt] = __builtin_amdgcn_mfma_i32_32x32x32_i8(      \
                        af[mt], B[nt * 2 + k], acc[mt][nt], 0, 0, 0);         \
            __builtin_amdgcn_s_setprio(0);                                    \
        }                                                                     \
    }

    // Prologue: stage A window 0 (tiles 0,1); load B ks=0,1 of tile 0;
    // drain; barrier.
    stage(0, 0);
    __builtin_amdgcn_sched_barrier(0);
    LOADB(B0, 0, 0)
    asm volatile("s_waitcnt vmcnt(0)" ::: "memory");
    __builtin_amdgcn_sched_barrier(0);
    __builtin_amdgcn_s_barrier();
    __builtin_amdgcn_sched_barrier(0);

    // 16 windows of BK=256. Windows 0..14 stage the next window; 15 below.
#pragma unroll 1
    for (int w = 0; w < 15; ++w) {
        const int8_t* a0 = sAf + (w & 1) * 32768;
        const int8_t* a1 = a0 + 16384;
        stage((w + 1) & 1, w + 1);
        __builtin_amdgcn_sched_barrier(0);
        LOADB(B1, 2 * w, 2)           // tile 2w, ks 2,3
        HALF(a0, B0, 0)               // tile 2w, ks 0,1
        LOADB(B0, 2 * w + 1, 0)       // tile 2w+1, ks 0,1
        HALF(a0, B1, 2)               // tile 2w, ks 2,3
        LOADB(B1, 2 * w + 1, 2)       // tile 2w+1, ks 2,3
        HALF(a1, B0, 0)               // tile 2w+1, ks 0,1
        LOADB(B0, 2 * w + 2, 0)       // next window, tile 2w+2, ks 0,1
        HALF(a1, B1, 2)               // tile 2w+1, ks 2,3 (wait drains stage)
        asm volatile("s_waitcnt vmcnt(4)" ::: "memory");  // keep only B0(next)
        __builtin_amdgcn_sched_barrier(0);
        __builtin_amdgcn_s_barrier();
        __builtin_amdgcn_sched_barrier(0);
    }
    // Window 15 (slot 1, tiles 30,31): no staging, no next-window B.
    {
        const int8_t* a0 = sAf + 32768;
        const int8_t* a1 = a0 + 16384;
        LOADB(B1, 30, 2)
        HALF(a0, B0, 0)
        LOADB(B0, 31, 0)
        HALF(a0, B1, 2)
        LOADB(B1, 31, 2)
        HALF(a1, B0, 0)
        HALF(a1, B1, 2)
    }

    // Epilogue: dequant + store. 32x32 C/D layout: col = lane&31,
    // row = (reg&3) + 8*(reg>>2) + 4*(lane>>5). (v8/v12-v17-verified.)
    const float ls = 127.0f / fmaxf(__uint_as_float(amax[0]), 1e-12f);
    const float rs = 127.0f / fmaxf(__uint_as_float(amax[1]), 1e-12f);
    const float inv = 1.0f / (ls * rs);
#pragma unroll
    for (int mt = 0; mt < 4; ++mt)
#pragma unroll
        for (int nt = 0; nt < 2; ++nt)
#pragma unroll
            for (int reg = 0; reg < 16; ++reg) {
                const int row = m0 + mt * 32 + (reg & 3) + 8 * (reg >> 2) +
                                4 * hi;
                const int col = n0 + wn * 64 + nt * 32 + rl;
                out[(size_t)row * NROW + col] = (float)acc[mt][nt][reg] * inv;
            }
#undef LOADB
#undef HALF
}

extern "C" void kernel_launch(void* const* d_in, const int* in_sizes, int n_in,
                              void* d_out, int out_size, void* d_ws,
                              size_t ws_size, hipStream_t stream) {
    const float* lhs = (const float*)d_in[0];
    const float* rhs = (const float*)d_in[1];
    float* out = (float*)d_out;

    int8_t* qA = (int8_t*)d_ws;
    int8_t* qBT = qA + (size_t)16 * 1024 * 1024;
    unsigned* amax = (unsigned*)(qBT + (size_t)16 * 1024 * 1024);

    hipMemsetAsync(amax, 0, 8, stream);
    absmax_both_kernel<<<2048, 256, 0, stream>>>(lhs, rhs, amax);
    quant_kernel<<<4096 + 4096, 256, 0, stream>>>(lhs, rhs, qA, qBT, amax);
    gemm_i8_kernel<<<dim3(16, 32), 256, 0, stream>>>(qA, qBT, out, amax);
}

// Round 20
// 135.901 us; speedup vs baseline: 1.6341x; 1.0120x over previous
//
#include <hip/hip_runtime.h>
#include <stdint.h>

// out = dequant( int8(lhs*ls) @ int8(rhs*rs) ) / (ls*rs), 4096^3, fp32 in/out.
// ls = 127 / max(amax|lhs|, 1e-12). Int core is bit-exact vs numpy (RNE quant).
//
// Workspace: [0,16Mi) qA frag-order ; [16Mi,32Mi) qBT frag-order ; 2x u32 amax.
//
// v20 = v16 (137.5us total, GEMM 71.3us) with ONE change: B-prefetch
// distance doubled at zero register cost. v16 issued each LOADB one HALF
// (~585 cyc) before consumption -- shorter than HBM-miss latency (~900 cyc;
// FETCH=125MB shows real HBM traffic on B), so both waves of a SIMD stall
// together on the B-wait and the MFMA pipe drains (pipe-sum analysis:
// observed 10.7k cyc/window ~= serial sum of MFMA 4.7k + VMEM 3.0k + LDS
// 2.5k; overlap requires each wave to have issuable work during waits).
// v20 rotates each LOADB to AFTER the HALF that frees its register set:
// every B-group now has ~2 HALF bodies (~1100-1200 cyc) of cover. The 2-set
// (B0/B1) rotation stays consistent: window w loads q2,q3 of w and q0,q1 of
// w+1. vmcnt(16) before the barrier retires exactly the 8 stage loads while
// all 16 B-loads stay in flight; compiler dependency-waits cover B.
//
// GEMM structure (v16-verified): 128x256 tile, 4 waves (1Mx4N of 128x64),
// frag-ordered workspace, mfma_i32_32x32x32_i8, A via conflict-free linear
// LDS (prefetch-1 window, double-buffered 2x32KiB), B global-direct register
// prefetch, BK=256 windows, 2 blocks/CU, XCD-aware swizzle. Measured optima:
// domains/CU=2 (v13/14/15), BK=256 (v14/16), 32x32x32+frag-order (v12).
//
// Layouts (all harness-verified, absmax 0.0 in v8/v10-v19):
//   frag (t_g, ks_g) at ((t_g*128 + ks_g)*64 + lane)*16; lane l holds
//   [t_g*32+(l&31)][ks_g*32+(l>>5)*16 .. +16).
//   C/D 32x32: col = lane&31, row = (reg&3) + 8*(reg>>2) + 4*(lane>>5).

#define NROW 4096
#define NELEM (4096 * 4096)

typedef __attribute__((ext_vector_type(4))) int int32x4;
typedef __attribute__((ext_vector_type(16))) int int32x16;
typedef const __attribute__((address_space(1))) int8_t* gptr1_t;
typedef __attribute__((address_space(3))) int8_t* lptr3_t;

__global__ void absmax_both_kernel(const float* __restrict__ lhs,
                                   const float* __restrict__ rhs,
                                   unsigned* __restrict__ amax) {
    __shared__ float red[4];
    const int t = blockIdx.x & 1;
    const float4* x4 = (const float4*)(t ? rhs : lhs);
    const int bid = blockIdx.x >> 1;
    const int stride = (gridDim.x >> 1) * blockDim.x;  // 262144
    int i = bid * blockDim.x + threadIdx.x;
    float m0 = 0.0f, m1 = 0.0f, m2 = 0.0f, m3 = 0.0f;
    for (; i + 3 * stride < NELEM / 4; i += 4 * stride) {
        float4 a = x4[i];
        float4 b = x4[i + stride];
        float4 c = x4[i + 2 * stride];
        float4 d = x4[i + 3 * stride];
        m0 = fmaxf(m0, fmaxf(fmaxf(fabsf(a.x), fabsf(a.y)),
                             fmaxf(fabsf(a.z), fabsf(a.w))));
        m1 = fmaxf(m1, fmaxf(fmaxf(fabsf(b.x), fabsf(b.y)),
                             fmaxf(fabsf(b.z), fabsf(b.w))));
        m2 = fmaxf(m2, fmaxf(fmaxf(fabsf(c.x), fabsf(c.y)),
                             fmaxf(fabsf(c.z), fabsf(c.w))));
        m3 = fmaxf(m3, fmaxf(fmaxf(fabsf(d.x), fabsf(d.y)),
                             fmaxf(fabsf(d.z), fabsf(d.w))));
    }
    for (; i < NELEM / 4; i += stride) {
        float4 a = x4[i];
        m0 = fmaxf(m0, fmaxf(fmaxf(fabsf(a.x), fabsf(a.y)),
                             fmaxf(fabsf(a.z), fabsf(a.w))));
    }
    float m = fmaxf(fmaxf(m0, m1), fmaxf(m2, m3));
    for (int off = 32; off > 0; off >>= 1)
        m = fmaxf(m, __shfl_down(m, off, 64));
    const int lane = threadIdx.x & 63, wave = threadIdx.x >> 6;
    if (lane == 0) red[wave] = m;
    __syncthreads();
    if (threadIdx.x == 0) {
        float b = fmaxf(fmaxf(red[0], red[1]), fmaxf(red[2], red[3]));
        atomicMax(amax + t, __float_as_uint(b));  // |x|>=0: bits monotone as uint
    }
}

__device__ __forceinline__ int q8(float v, float s) {
    int r = __float2int_rn(v * s);  // RNE, matches jnp.round
    r = r < -127 ? -127 : r;
    r = r > 127 ? 127 : r;
    return r;
}

__device__ __forceinline__ int pack4(float a, float b, float c, float d,
                                     float s) {
    return (q8(a, s) & 0xff) | ((q8(b, s) & 0xff) << 8) |
           ((q8(c, s) & 0xff) << 16) | ((q8(d, s) & 0xff) << 24);
}

// Blocks [0,4096): A -> fragment layout (thread t = chunk c: contiguous 16B
// store to qA+c*16 from a 64B row-segment of lhs). Blocks [4096,8192): B ->
// verified LDS 64x64 transpose, frag-order output. (v10-v19 verified.)
__global__ void quant_kernel(const float* __restrict__ lhs,
                             const float* __restrict__ rhs,
                             int8_t* __restrict__ qA, int8_t* __restrict__ qT,
                             const unsigned* __restrict__ amax) {
    __shared__ int8_t sm[64][68];
    if (blockIdx.x < 4096) {
        const float s = 127.0f / fmaxf(__uint_as_float(amax[0]), 1e-12f);
        const int c = blockIdx.x * 256 + threadIdx.x;
        const int l = c & 63;
        const int ks_g = (c >> 6) & 127;
        const int mt_g = c >> 13;
        const int row = mt_g * 32 + (l & 31);
        const int kb = ks_g * 32 + (l >> 5) * 16;
        const float4* src = (const float4*)(lhs + (size_t)row * NROW + kb);
        float4 v0 = src[0], v1 = src[1], v2 = src[2], v3 = src[3];
        int4 w;
        w.x = pack4(v0.x, v0.y, v0.z, v0.w, s);
        w.y = pack4(v1.x, v1.y, v1.z, v1.w, s);
        w.z = pack4(v2.x, v2.y, v2.z, v2.w, s);
        w.w = pack4(v3.x, v3.y, v3.z, v3.w, s);
        *(int4*)(qA + (size_t)c * 16) = w;
    } else {
        const float s = 127.0f / fmaxf(__uint_as_float(amax[1]), 1e-12f);
        const int b = blockIdx.x - 4096;
        const int n0 = (b & 63) * 64, k0 = (b >> 6) * 64;
        const int rl = threadIdx.x >> 4;   // k row within 16-row slab
        const int nq = threadIdx.x & 15;   // float4 column
        for (int r = 0; r < 4; ++r) {
            const int kl = r * 16 + rl;
            float4 v = *(const float4*)(rhs + (size_t)(k0 + kl) * NROW + n0 + nq * 4);
            sm[nq * 4 + 0][kl] = (int8_t)q8(v.x, s);
            sm[nq * 4 + 1][kl] = (int8_t)q8(v.y, s);
            sm[nq * 4 + 2][kl] = (int8_t)q8(v.z, s);
            sm[nq * 4 + 3][kl] = (int8_t)q8(v.w, s);
        }
        __syncthreads();
        // Frag-order store: tile = 2 nt x 2 ks x 64 lanes = 256 chunks.
        const int nt_l = threadIdx.x >> 7;        // 0..1
        const int ks_l = (threadIdx.x >> 6) & 1;  // 0..1
        const int l = threadIdx.x & 63;
        const int n_loc = nt_l * 32 + (l & 31);
        const int k_loc = ks_l * 32 + (l >> 5) * 16;
        int4 w;  // 4x b32 reads, stride 17 words -> conflict-free
        w.x = *(const int*)&sm[n_loc][k_loc + 0];
        w.y = *(const int*)&sm[n_loc][k_loc + 4];
        w.z = *(const int*)&sm[n_loc][k_loc + 8];
        w.w = *(const int*)&sm[n_loc][k_loc + 12];
        const int nt_g = (b & 63) * 2 + nt_l;
        const int ks_g = (b >> 6) * 2 + ks_l;
        *(int4*)(qT + (((size_t)nt_g * 128 + ks_g) * 64 + l) * 16) = w;
    }
}

// 128x256 tile, 4 waves (1Mx4N of 128x64 = 4x2 of 32x32), BK=256 windows
// (2 K-tiles of 128 per barrier), 2 blocks/CU. A: double-buffered frag-
// ordered LDS (2 x 32 KiB), prefetch-1 window. B: global-direct register
// frags, distance-2 prefetch: each LOADB issued right AFTER the HALF that
// frees its set, consumed 2 HALFs (~1100 cyc) later. Window w (tiles
// 2w,2w+1): [stage A(w+1); HALF q0; LB(q2); HALF q1; LB(q3); HALF q2;
// LB(q0'); HALF q3; LB(q1'); vmcnt(16); s_barrier].
__global__ __launch_bounds__(256, 2) void gemm_i8_kernel(
    const int8_t* __restrict__ qA, const int8_t* __restrict__ qBT,
    float* __restrict__ out, const unsigned* __restrict__ amax) {
    __shared__ __align__(16) int8_t sA[2][32768];

    const int tid = threadIdx.x;
    const int lane = tid & 63;
    const int wn = tid >> 6;        // 0..3 : 64-col sub-tile

    // XCD-aware bijective swizzle (grid 512, 512%8==0): XCD k gets swz ids
    // [64k,64k+64) -> 4 contiguous 128-row M-panels (2 MB A) L2-resident.
    const int bid = blockIdx.y * 16 + blockIdx.x;
    const int swz = (bid & 7) * 64 + (bid >> 3);
    const int m0 = (swz >> 4) * 128, n0 = (swz & 15) * 256;

    const int rl = lane & 31;       // row within a 32-row MFMA tile
    const int hi = lane >> 5;       // k-half selector

    const gptr1_t pA0 = (gptr1_t)(qA + (size_t)(m0 / 32) * 131072 + tid * 16);
    int8_t* sAf = &sA[0][0];
    const int dst0 = tid * 16;

    auto stage = [&](int slot, int w1) {
#pragma unroll
        for (int h = 0; h < 2; ++h) {
            const int kb = (2 * w1 + h) * 4096;
#pragma unroll
            for (int j = 0; j < 4; ++j) {
                __builtin_amdgcn_global_load_lds(
                    pA0 + (size_t)j * 131072 + kb,
                    (lptr3_t)(sAf + slot * 32768 + h * 16384 + dst0 + j * 4096),
                    16, 0, 0);
            }
        }
    };

    const int8_t* pbW = qBT + (size_t)(n0 / 32 + wn * 2) * 131072 + lane * 16;

    int32x16 acc[4][2];
#pragma unroll
    for (int mt = 0; mt < 4; ++mt)
#pragma unroll
        for (int nt = 0; nt < 2; ++nt) acc[mt][nt] = (int32x16)(0);

    const int aBase = lane * 16;

    int32x4 B0[4], B1[4];  // [nt*2 + k] for a 2-ks quarter-phase

#define LOADB(B, KT, KS0)                                                     \
    {                                                                         \
        const int8_t* bp = pbW + (size_t)(KT)*4096 + (KS0)*1024;              \
        B[0] = *(const int32x4*)(bp);                                         \
        B[1] = *(const int32x4*)(bp + 1024);                                  \
        B[2] = *(const int32x4*)(bp + 131072);                                \
        B[3] = *(const int32x4*)(bp + 131072 + 1024);                         \
    }

#define HALF(APTR, B, KS0)                                                    \
    {                                                                         \
        _Pragma("unroll") for (int k = 0; k < 2; ++k) {                       \
            int32x4 af[4];                                                    \
            _Pragma("unroll") for (int mt = 0; mt < 4; ++mt) af[mt] =         \
                *(const int32x4*)((APTR) + aBase + mt * 4096 +                \
                                  ((KS0) + k) * 1024);                        \
            __builtin_amdgcn_s_setprio(1);                                    \
            _Pragma("unroll") for (int mt = 0; mt < 4; ++mt)                  \
                _Pragma("unroll") for (int nt = 0; nt < 2; ++nt)              \
                    acc[mt][nt] = __builtin_amdgcn_mfma_i32_32x32x32_i8(      \
                        af[mt], B[nt * 2 + k], acc[mt][nt], 0, 0, 0);         \
            __builtin_amdgcn_s_setprio(0);                                    \
        }                                                                     \
    }

    // Prologue: stage A window 0 (tiles 0,1); preload B q0=(0,ks01) and
    // q1=(0,ks23); drain; barrier.
    stage(0, 0);
    __builtin_amdgcn_sched_barrier(0);
    LOADB(B0, 0, 0)
    LOADB(B1, 0, 2)
    asm volatile("s_waitcnt vmcnt(0)" ::: "memory");
    __builtin_amdgcn_sched_barrier(0);
    __builtin_amdgcn_s_barrier();
    __builtin_amdgcn_sched_barrier(0);

    // 16 windows of BK=256. Windows 0..14 stage the next window; 15 below.
    // Quarter q_i of window w consumes set (i&1); its reload (for q_{i+2})
    // issues right after HALF q_i -> every B-load has ~2 HALFs of cover.
#pragma unroll 1
    for (int w = 0; w < 15; ++w) {
        const int8_t* a0 = sAf + (w & 1) * 32768;
        const int8_t* a1 = a0 + 16384;
        stage((w + 1) & 1, w + 1);
        __builtin_amdgcn_sched_barrier(0);
        HALF(a0, B0, 0)               // q0: tile 2w,   ks 0,1
        LOADB(B0, 2 * w + 1, 0)       //     -> q2: tile 2w+1, ks 0,1
        HALF(a0, B1, 2)               // q1: tile 2w,   ks 2,3
        LOADB(B1, 2 * w + 1, 2)       //     -> q3: tile 2w+1, ks 2,3
        HALF(a1, B0, 0)               // q2
        LOADB(B0, 2 * w + 2, 0)       //     -> next q0: tile 2w+2, ks 0,1
        HALF(a1, B1, 2)               // q3
        LOADB(B1, 2 * w + 2, 2)       //     -> next q1: tile 2w+2, ks 2,3
        asm volatile("s_waitcnt vmcnt(16)" ::: "memory");  // retire stage only
        __builtin_amdgcn_sched_barrier(0);
        __builtin_amdgcn_s_barrier();
        __builtin_amdgcn_sched_barrier(0);
    }
    // Window 15 (slot 1, tiles 30,31): no staging, no next-window B.
    {
        const int8_t* a0 = sAf + 32768;
        const int8_t* a1 = a0 + 16384;
        HALF(a0, B0, 0)               // (30, ks01)
        LOADB(B0, 31, 0)
        HALF(a0, B1, 2)               // (30, ks23)
        LOADB(B1, 31, 2)
        HALF(a1, B0, 0)               // (31, ks01)
        HALF(a1, B1, 2)               // (31, ks23)
    }

    // Epilogue: dequant + store. 32x32 C/D layout: col = lane&31,
    // row = (reg&3) + 8*(reg>>2) + 4*(lane>>5). (v8/v12-v19-verified.)
    const float ls = 127.0f / fmaxf(__uint_as_float(amax[0]), 1e-12f);
    const float rs = 127.0f / fmaxf(__uint_as_float(amax[1]), 1e-12f);
    const float inv = 1.0f / (ls * rs);
#pragma unroll
    for (int mt = 0; mt < 4; ++mt)
#pragma unroll
        for (int nt = 0; nt < 2; ++nt)
#pragma unroll
            for (int reg = 0; reg < 16; ++reg) {
                const int row = m0 + mt * 32 + (reg & 3) + 8 * (reg >> 2) +
                                4 * hi;
                const int col = n0 + wn * 64 + nt * 32 + rl;
                out[(size_t)row * NROW + col] = (float)acc[mt][nt][reg] * inv;
            }
#undef LOADB
#undef HALF
}

extern "C" void kernel_launch(void* const* d_in, const int* in_sizes, int n_in,
                              void* d_out, int out_size, void* d_ws,
                              size_t ws_size, hipStream_t stream) {
    const float* lhs = (const float*)d_in[0];
    const float* rhs = (const float*)d_in[1];
    float* out = (float*)d_out;

    int8_t* qA = (int8_t*)d_ws;
    int8_t* qBT = qA + (size_t)16 * 1024 * 1024;
    unsigned* amax = (unsigned*)(qBT + (size_t)16 * 1024 * 1024);

    hipMemsetAsync(amax, 0, 8, stream);
    absmax_both_kernel<<<2048, 256, 0, stream>>>(lhs, rhs, amax);
    quant_kernel<<<4096 + 4096, 256, 0, stream>>>(lhs, rhs, qA, qBT, amax);
    gemm_i8_kernel<<<dim3(16, 32), 256, 0, stream>>>(qA, qBT, out, amax);
}

// Round 21
// 135.828 us; speedup vs baseline: 1.6350x; 1.0005x over previous
//
#include <hip/hip_runtime.h>
#include <stdint.h>

// out = dequant( int8(lhs*ls) @ int8(rhs*rs) ) / (ls*rs), 4096^3, fp32 in/out.
// ls = 127 / max(amax|lhs|, 1e-12). Int core is bit-exact vs numpy (RNE quant).
//
// Workspace: [0,16Mi) qA frag-order ; [16Mi,32Mi) qBT frag-order ; 2x u32 amax.
//
// v21 = v20 (135.9us total, GEMM 70.5us) + CO-RESIDENT BLOCK STAGGER.
// v20's window is ~10.4k cyc vs serial pipe-sum 10.2k: the VMEM/LDS/MFMA
// pipes still serialize because the 2 blocks sharing each CU run IDENTICAL
// schedules -- their VMEM bursts align, draining the MFMA pipe together.
// HW dispatches blocks round-robin over 256 CUs, so co-resident pairs are
// (bid, bid+256): differ in original-id bit 8. v21 keys the intra-window
// ORDER of the same work on p = (bid>>8)&1 (math identical -- K-sum is
// order-free): p=0 stages A at window start (vmcnt(16)); p=1 stages A
// mid-window after q1 (vmcnt(8): in-order queue at window end = stage 8 +
// next-window B 8; retiring to 8 drains exactly the stage). When p=0 bursts
// loads, its CU-mate is mid-MFMA, and vice versa.
//
// GEMM structure (v16/v20-verified): 128x256 tile, 4 waves (1Mx4N of
// 128x64), frag-ordered workspace, mfma_i32_32x32x32_i8, A conflict-free
// linear LDS (prefetch-1 window, 2x32KiB), B global-direct register
// prefetch distance-2, BK=256 windows, 2 blocks/CU, XCD swizzle. Measured
// optima: domains/CU=2 (v13/14/15), BK=256 (v14/16), dist-2 B (v20).
//
// Layouts (all harness-verified, absmax 0.0 in v8/v10-v20):
//   frag (t_g, ks_g) at ((t_g*128 + ks_g)*64 + lane)*16; lane l holds
//   [t_g*32+(l&31)][ks_g*32+(l>>5)*16 .. +16).
//   C/D 32x32: col = lane&31, row = (reg&3) + 8*(reg>>2) + 4*(lane>>5).

#define NROW 4096
#define NELEM (4096 * 4096)

typedef __attribute__((ext_vector_type(4))) int int32x4;
typedef __attribute__((ext_vector_type(16))) int int32x16;
typedef const __attribute__((address_space(1))) int8_t* gptr1_t;
typedef __attribute__((address_space(3))) int8_t* lptr3_t;

__global__ void absmax_both_kernel(const float* __restrict__ lhs,
                                   const float* __restrict__ rhs,
                                   unsigned* __restrict__ amax) {
    __shared__ float red[4];
    const int t = blockIdx.x & 1;
    const float4* x4 = (const float4*)(t ? rhs : lhs);
    const int bid = blockIdx.x >> 1;
    const int stride = (gridDim.x >> 1) * blockDim.x;  // 262144
    int i = bid * blockDim.x + threadIdx.x;
    float m0 = 0.0f, m1 = 0.0f, m2 = 0.0f, m3 = 0.0f;
    for (; i + 3 * stride < NELEM / 4; i += 4 * stride) {
        float4 a = x4[i];
        float4 b = x4[i + stride];
        float4 c = x4[i + 2 * stride];
        float4 d = x4[i + 3 * stride];
        m0 = fmaxf(m0, fmaxf(fmaxf(fabsf(a.x), fabsf(a.y)),
                             fmaxf(fabsf(a.z), fabsf(a.w))));
        m1 = fmaxf(m1, fmaxf(fmaxf(fabsf(b.x), fabsf(b.y)),
                             fmaxf(fabsf(b.z), fabsf(b.w))));
        m2 = fmaxf(m2, fmaxf(fmaxf(fabsf(c.x), fabsf(c.y)),
                             fmaxf(fabsf(c.z), fabsf(c.w))));
        m3 = fmaxf(m3, fmaxf(fmaxf(fabsf(d.x), fabsf(d.y)),
                             fmaxf(fabsf(d.z), fabsf(d.w))));
    }
    for (; i < NELEM / 4; i += stride) {
        float4 a = x4[i];
        m0 = fmaxf(m0, fmaxf(fmaxf(fabsf(a.x), fabsf(a.y)),
                             fmaxf(fabsf(a.z), fabsf(a.w))));
    }
    float m = fmaxf(fmaxf(m0, m1), fmaxf(m2, m3));
    for (int off = 32; off > 0; off >>= 1)
        m = fmaxf(m, __shfl_down(m, off, 64));
    const int lane = threadIdx.x & 63, wave = threadIdx.x >> 6;
    if (lane == 0) red[wave] = m;
    __syncthreads();
    if (threadIdx.x == 0) {
        float b = fmaxf(fmaxf(red[0], red[1]), fmaxf(red[2], red[3]));
        atomicMax(amax + t, __float_as_uint(b));  // |x|>=0: bits monotone as uint
    }
}

__device__ __forceinline__ int q8(float v, float s) {
    int r = __float2int_rn(v * s);  // RNE, matches jnp.round
    r = r < -127 ? -127 : r;
    r = r > 127 ? 127 : r;
    return r;
}

__device__ __forceinline__ int pack4(float a, float b, float c, float d,
                                     float s) {
    return (q8(a, s) & 0xff) | ((q8(b, s) & 0xff) << 8) |
           ((q8(c, s) & 0xff) << 16) | ((q8(d, s) & 0xff) << 24);
}

// Blocks [0,4096): A -> fragment layout (thread t = chunk c: contiguous 16B
// store to qA+c*16 from a 64B row-segment of lhs). Blocks [4096,8192): B ->
// verified LDS 64x64 transpose, frag-order output. (v10-v20 verified.)
__global__ void quant_kernel(const float* __restrict__ lhs,
                             const float* __restrict__ rhs,
                             int8_t* __restrict__ qA, int8_t* __restrict__ qT,
                             const unsigned* __restrict__ amax) {
    __shared__ int8_t sm[64][68];
    if (blockIdx.x < 4096) {
        const float s = 127.0f / fmaxf(__uint_as_float(amax[0]), 1e-12f);
        const int c = blockIdx.x * 256 + threadIdx.x;
        const int l = c & 63;
        const int ks_g = (c >> 6) & 127;
        const int mt_g = c >> 13;
        const int row = mt_g * 32 + (l & 31);
        const int kb = ks_g * 32 + (l >> 5) * 16;
        const float4* src = (const float4*)(lhs + (size_t)row * NROW + kb);
        float4 v0 = src[0], v1 = src[1], v2 = src[2], v3 = src[3];
        int4 w;
        w.x = pack4(v0.x, v0.y, v0.z, v0.w, s);
        w.y = pack4(v1.x, v1.y, v1.z, v1.w, s);
        w.z = pack4(v2.x, v2.y, v2.z, v2.w, s);
        w.w = pack4(v3.x, v3.y, v3.z, v3.w, s);
        *(int4*)(qA + (size_t)c * 16) = w;
    } else {
        const float s = 127.0f / fmaxf(__uint_as_float(amax[1]), 1e-12f);
        const int b = blockIdx.x - 4096;
        const int n0 = (b & 63) * 64, k0 = (b >> 6) * 64;
        const int rl = threadIdx.x >> 4;   // k row within 16-row slab
        const int nq = threadIdx.x & 15;   // float4 column
        for (int r = 0; r < 4; ++r) {
            const int kl = r * 16 + rl;
            float4 v = *(const float4*)(rhs + (size_t)(k0 + kl) * NROW + n0 + nq * 4);
            sm[nq * 4 + 0][kl] = (int8_t)q8(v.x, s);
            sm[nq * 4 + 1][kl] = (int8_t)q8(v.y, s);
            sm[nq * 4 + 2][kl] = (int8_t)q8(v.z, s);
            sm[nq * 4 + 3][kl] = (int8_t)q8(v.w, s);
        }
        __syncthreads();
        // Frag-order store: tile = 2 nt x 2 ks x 64 lanes = 256 chunks.
        const int nt_l = threadIdx.x >> 7;        // 0..1
        const int ks_l = (threadIdx.x >> 6) & 1;  // 0..1
        const int l = threadIdx.x & 63;
        const int n_loc = nt_l * 32 + (l & 31);
        const int k_loc = ks_l * 32 + (l >> 5) * 16;
        int4 w;  // 4x b32 reads, stride 17 words -> conflict-free
        w.x = *(const int*)&sm[n_loc][k_loc + 0];
        w.y = *(const int*)&sm[n_loc][k_loc + 4];
        w.z = *(const int*)&sm[n_loc][k_loc + 8];
        w.w = *(const int*)&sm[n_loc][k_loc + 12];
        const int nt_g = (b & 63) * 2 + nt_l;
        const int ks_g = (b >> 6) * 2 + ks_l;
        *(int4*)(qT + (((size_t)nt_g * 128 + ks_g) * 64 + l) * 16) = w;
    }
}

// 128x256 tile, 4 waves (1Mx4N of 128x64 = 4x2 of 32x32), BK=256 windows,
// 2 blocks/CU. A: double-buffered frag-ordered LDS (2 x 32 KiB), prefetch-1
// window. B: global-direct register frags, distance-2 prefetch. Two
// schedule variants of the SAME work keyed on co-residency parity p:
//   p=0: [stage; HALF q0; LB; HALF q1; LB; HALF q2; LB; HALF q3; LB;
//         vmcnt(16); bar]   (v20's body)
//   p=1: [HALF q0; LB; HALF q1; LB; stage; HALF q2; LB; HALF q3; LB;
//         vmcnt(8); bar]    (stage mid-window; queue at end = stage8 + B8)
__global__ __launch_bounds__(256, 2) void gemm_i8_kernel(
    const int8_t* __restrict__ qA, const int8_t* __restrict__ qBT,
    float* __restrict__ out, const unsigned* __restrict__ amax) {
    __shared__ __align__(16) int8_t sA[2][32768];

    const int tid = threadIdx.x;
    const int lane = tid & 63;
    const int wn = tid >> 6;        // 0..3 : 64-col sub-tile

    // XCD-aware bijective swizzle (grid 512, 512%8==0): XCD k gets swz ids
    // [64k,64k+64) -> 4 contiguous 128-row M-panels (2 MB A) L2-resident.
    const int bid = blockIdx.y * 16 + blockIdx.x;
    const int swz = (bid & 7) * 64 + (bid >> 3);
    const int m0 = (swz >> 4) * 128, n0 = (swz & 15) * 256;
    // Co-resident pairing: round-robin dispatch over 256 CUs puts original
    // ids bid and bid+256 on the same CU -> parity = bit 8.
    const int p = (bid >> 8) & 1;

    const int rl = lane & 31;       // row within a 32-row MFMA tile
    const int hi = lane >> 5;       // k-half selector

    const gptr1_t pA0 = (gptr1_t)(qA + (size_t)(m0 / 32) * 131072 + tid * 16);
    int8_t* sAf = &sA[0][0];
    const int dst0 = tid * 16;

    auto stage = [&](int slot, int w1) {
#pragma unroll
        for (int h = 0; h < 2; ++h) {
            const int kb = (2 * w1 + h) * 4096;
#pragma unroll
            for (int j = 0; j < 4; ++j) {
                __builtin_amdgcn_global_load_lds(
                    pA0 + (size_t)j * 131072 + kb,
                    (lptr3_t)(sAf + slot * 32768 + h * 16384 + dst0 + j * 4096),
                    16, 0, 0);
            }
        }
    };

    const int8_t* pbW = qBT + (size_t)(n0 / 32 + wn * 2) * 131072 + lane * 16;

    int32x16 acc[4][2];
#pragma unroll
    for (int mt = 0; mt < 4; ++mt)
#pragma unroll
        for (int nt = 0; nt < 2; ++nt) acc[mt][nt] = (int32x16)(0);

    const int aBase = lane * 16;

    int32x4 B0[4], B1[4];  // [nt*2 + k] for a 2-ks quarter-phase

#define LOADB(B, KT, KS0)                                                     \
    {                                                                         \
        const int8_t* bp = pbW + (size_t)(KT)*4096 + (KS0)*1024;              \
        B[0] = *(const int32x4*)(bp);                                         \
        B[1] = *(const int32x4*)(bp + 1024);                                  \
        B[2] = *(const int32x4*)(bp + 131072);                                \
        B[3] = *(const int32x4*)(bp + 131072 + 1024);                         \
    }

#define HALF(APTR, B, KS0)                                                    \
    {                                                                         \
        _Pragma("unroll") for (int k = 0; k < 2; ++k) {                       \
            int32x4 af[4];                                                    \
            _Pragma("unroll") for (int mt = 0; mt < 4; ++mt) af[mt] =         \
                *(const int32x4*)((APTR) + aBase + mt * 4096 +                \
                                  ((KS0) + k) * 1024);                        \
            __builtin_amdgcn_s_setprio(1);                                    \
            _Pragma("unroll") for (int mt = 0; mt < 4; ++mt)                  \
                _Pragma("unroll") for (int nt = 0; nt < 2; ++nt)              \
                    acc[mt][nt] = __builtin_amdgcn_mfma_i32_32x32x32_i8(      \
                        af[mt], B[nt * 2 + k], acc[mt][nt], 0, 0, 0);         \
            __builtin_amdgcn_s_setprio(0);                                    \
        }                                                                     \
    }

    // Prologue (both parities): stage A window 0; preload B q0,q1; drain.
    stage(0, 0);
    __builtin_amdgcn_sched_barrier(0);
    LOADB(B0, 0, 0)
    LOADB(B1, 0, 2)
    asm volatile("s_waitcnt vmcnt(0)" ::: "memory");
    __builtin_amdgcn_sched_barrier(0);
    __builtin_amdgcn_s_barrier();
    __builtin_amdgcn_sched_barrier(0);

    if (p == 0) {
        // v20 body: stage at window start; vmcnt(16) retires it at end.
#pragma unroll 1
        for (int w = 0; w < 15; ++w) {
            const int8_t* a0 = sAf + (w & 1) * 32768;
            const int8_t* a1 = a0 + 16384;
            stage((w + 1) & 1, w + 1);
            __builtin_amdgcn_sched_barrier(0);
            HALF(a0, B0, 0)
            LOADB(B0, 2 * w + 1, 0)
            HALF(a0, B1, 2)
            LOADB(B1, 2 * w + 1, 2)
            HALF(a1, B0, 0)
            LOADB(B0, 2 * w + 2, 0)
            HALF(a1, B1, 2)
            LOADB(B1, 2 * w + 2, 2)
            asm volatile("s_waitcnt vmcnt(16)" ::: "memory");
            __builtin_amdgcn_sched_barrier(0);
            __builtin_amdgcn_s_barrier();
            __builtin_amdgcn_sched_barrier(0);
        }
    } else {
        // Staggered body: stage mid-window (after q1). At window end the
        // in-order queue = stage 8 + next-window B 8 -> vmcnt(8) retires
        // exactly the stage (B-loads stay in flight). Dependency waits for
        // q2/q3's B-groups (issued before the stage) leave the stage
        // outstanding, so vmcnt(8) is the first point that retires it.
#pragma unroll 1
        for (int w = 0; w < 15; ++w) {
            const int8_t* a0 = sAf + (w & 1) * 32768;
            const int8_t* a1 = a0 + 16384;
            HALF(a0, B0, 0)
            LOADB(B0, 2 * w + 1, 0)
            HALF(a0, B1, 2)
            LOADB(B1, 2 * w + 1, 2)
            stage((w + 1) & 1, w + 1);
            __builtin_amdgcn_sched_barrier(0);
            HALF(a1, B0, 0)
            LOADB(B0, 2 * w + 2, 0)
            HALF(a1, B1, 2)
            LOADB(B1, 2 * w + 2, 2)
            asm volatile("s_waitcnt vmcnt(8)" ::: "memory");
            __builtin_amdgcn_sched_barrier(0);
            __builtin_amdgcn_s_barrier();
            __builtin_amdgcn_sched_barrier(0);
        }
    }
    // Window 15 (slot 1, tiles 30,31): no staging, no next-window B.
    {
        const int8_t* a0 = sAf + 32768;
        const int8_t* a1 = a0 + 16384;
        HALF(a0, B0, 0)               // (30, ks01)
        LOADB(B0, 31, 0)
        HALF(a0, B1, 2)               // (30, ks23)
        LOADB(B1, 31, 2)
        HALF(a1, B0, 0)               // (31, ks01)
        HALF(a1, B1, 2)               // (31, ks23)
    }

    // Epilogue: dequant + store. 32x32 C/D layout: col = lane&31,
    // row = (reg&3) + 8*(reg>>2) + 4*(lane>>5). (v8/v12-v20-verified.)
    const float ls = 127.0f / fmaxf(__uint_as_float(amax[0]), 1e-12f);
    const float rs = 127.0f / fmaxf(__uint_as_float(amax[1]), 1e-12f);
    const float inv = 1.0f / (ls * rs);
#pragma unroll
    for (int mt = 0; mt < 4; ++mt)
#pragma unroll
        for (int nt = 0; nt < 2; ++nt)
#pragma unroll
            for (int reg = 0; reg < 16; ++reg) {
                const int row = m0 + mt * 32 + (reg & 3) + 8 * (reg >> 2) +
                                4 * hi;
                const int col = n0 + wn * 64 + nt * 32 + rl;
                out[(size_t)row * NROW + col] = (float)acc[mt][nt][reg] * inv;
            }
#undef LOADB
#undef HALF
}

extern "C" void kernel_launch(void* const* d_in, const int* in_sizes, int n_in,
                              void* d_out, int out_size, void* d_ws,
                              size_t ws_size, hipStream_t stream) {
    const float* lhs = (const float*)d_in[0];
    const float* rhs = (const float*)d_in[1];
    float* out = (float*)d_out;

    int8_t* qA = (int8_t*)d_ws;
    int8_t* qBT = qA + (size_t)16 * 1024 * 1024;
    unsigned* amax = (unsigned*)(qBT + (size_t)16 * 1024 * 1024);

    hipMemsetAsync(amax, 0, 8, stream);
    absmax_both_kernel<<<2048, 256, 0, stream>>>(lhs, rhs, amax);
    quant_kernel<<<4096 + 4096, 256, 0, stream>>>(lhs, rhs, qA, qBT, amax);
    gemm_i8_kernel<<<dim3(16, 32), 256, 0, stream>>>(qA, qBT, out, amax);
}